// Round 4
// baseline (1140.324 us; speedup 1.0000x reference)
//
#include <hip/hip_runtime.h>
#include <hip/hip_bf16.h>
#include <stdint.h>

#define LN_EPS 1e-5f

typedef __attribute__((ext_vector_type(8))) __bf16 bf16x8;
typedef __attribute__((ext_vector_type(8))) short short8;
typedef __attribute__((ext_vector_type(4))) float floatx4;

__device__ __forceinline__ ushort f2bf(float f) {
    __hip_bfloat16 h = __float2bfloat16(f);
    return *reinterpret_cast<ushort*>(&h);
}
__device__ __forceinline__ float bf2f(ushort u) {
    return __builtin_bit_cast(float, ((unsigned int)u) << 16);
}

// async global->LDS, 16B per lane; LDS dest = wave-uniform base + lane*16
__device__ __forceinline__ void gload16(const void* g, void* l) {
#if __has_builtin(__builtin_amdgcn_global_load_lds)
    __builtin_amdgcn_global_load_lds(
        (const __attribute__((address_space(1))) unsigned int*)g,
        (__attribute__((address_space(3))) unsigned int*)l, 16, 0, 0);
#else
    *(int4*)l = *(const int4*)g;
#endif
}

// ---------------------------------------------------------------------------
// GEMM: C[M,N] = A[M,K](bf16 rm, lda) x Bt[N,K](bf16 rm, ldb)  (Bt = B^T)
// 128x128 tile, BK=32, 256 thr (4 waves 2x2 of 64x64), mfma 16x16x32 bf16.
// EPI: 0 bf16 | 1 bf16 sigmoid | 2 bf16 relu^2 | 3 f32 out=add0+mul0*acc
//      4 bf16 transposed (idx = n*ldc + m) | 5 bf16 sigmoid transposed
// ---------------------------------------------------------------------------
template <int EPI>
__global__ __launch_bounds__(256, 2) void gemm_bt(
    const ushort* __restrict__ A, const ushort* __restrict__ Bt,
    int N, int K, int lda, int ldb, int ldc,
    float* __restrict__ outF, ushort* __restrict__ outB,
    const float* __restrict__ add0, const ushort* __restrict__ mul0) {
    __shared__ __align__(16) ushort As[128 * 32];
    __shared__ __align__(16) ushort Bs[128 * 32];

    const int tid  = threadIdx.x;
    const int lane = tid & 63;
    const int wv   = tid >> 6;
    const int quad = lane >> 4;
    const int l16  = lane & 15;
    const int wm   = (wv >> 1) * 64;
    const int wn   = (wv & 1) * 64;
    const long m0 = (long)blockIdx.y * 128;
    const long n0 = (long)blockIdx.x * 128;

    floatx4 acc[4][4];
#pragma unroll
    for (int i = 0; i < 4; i++)
#pragma unroll
        for (int j = 0; j < 4; j++) acc[i][j] = (floatx4)0.f;

    const int ci0 = tid, ci1 = tid + 256;
    const int r0 = ci0 >> 2, kc0 = (ci0 & 3) * 8;
    const int r1 = ci1 >> 2, kc1 = (ci1 & 3) * 8;
    const ushort* Ab0 = A + (m0 + r0) * (long)lda + kc0;
    const ushort* Ab1 = A + (m0 + r1) * (long)lda + kc1;
    const ushort* Bb0 = Bt + (n0 + r0) * (long)ldb + kc0;
    const ushort* Bb1 = Bt + (n0 + r1) * (long)ldb + kc1;

    for (int k0 = 0; k0 < K; k0 += 32) {
        gload16(Ab0 + k0, &As[ci0 * 8]);
        gload16(Ab1 + k0, &As[ci1 * 8]);
        gload16(Bb0 + k0, &Bs[ci0 * 8]);
        gload16(Bb1 + k0, &Bs[ci1 * 8]);
        __syncthreads();

        bf16x8 a[4], b[4];
#pragma unroll
        for (int mi = 0; mi < 4; mi++)
            a[mi] = __builtin_bit_cast(
                bf16x8, *(const short8*)&As[(wm + mi * 16 + l16) * 32 + quad * 8]);
#pragma unroll
        for (int ni = 0; ni < 4; ni++)
            b[ni] = __builtin_bit_cast(
                bf16x8, *(const short8*)&Bs[(wn + ni * 16 + l16) * 32 + quad * 8]);
#pragma unroll
        for (int mi = 0; mi < 4; mi++)
#pragma unroll
            for (int ni = 0; ni < 4; ni++)
                acc[mi][ni] = __builtin_amdgcn_mfma_f32_16x16x32_bf16(
                    a[mi], b[ni], acc[mi][ni], 0, 0, 0);
        __syncthreads();
    }

    // C/D layout: col = lane&15, row = quad*4 + reg (m89/m91-verified)
#pragma unroll
    for (int mi = 0; mi < 4; mi++) {
#pragma unroll
        for (int ni = 0; ni < 4; ni++) {
            long n = n0 + wn + ni * 16 + l16;
            if constexpr (EPI == 4 || EPI == 5) {
                long mb = m0 + wm + mi * 16 + quad * 4;
                ushort4 pk;
#pragma unroll
                for (int r = 0; r < 4; r++) {
                    float v = acc[mi][ni][r];
                    if constexpr (EPI == 5) v = 1.f / (1.f + __expf(-v));
                    ((ushort*)&pk)[r] = f2bf(v);
                }
                *(ushort4*)&outB[n * (long)ldc + mb] = pk;
            } else {
#pragma unroll
                for (int r = 0; r < 4; r++) {
                    long m = m0 + wm + mi * 16 + quad * 4 + r;
                    long idx = m * (long)ldc + n;
                    float v = acc[mi][ni][r];
                    if constexpr (EPI == 0) {
                        outB[idx] = f2bf(v);
                    } else if constexpr (EPI == 1) {
                        outB[idx] = f2bf(1.f / (1.f + __expf(-v)));
                    } else if constexpr (EPI == 2) {
                        float t = fmaxf(v, 0.f);
                        outB[idx] = f2bf(t * t);
                    } else if constexpr (EPI == 3) {
                        outF[idx] = add0[idx] + bf2f(mul0[idx]) * v;
                    }
                }
            }
        }
    }
}

// ---------------------------------------------------------------------------
// Fused LayerNorm + time-shift + mix -> bf16 outputs (3 mixes), f32 input.
// ---------------------------------------------------------------------------
__global__ __launch_bounds__(256) void ln_mix3(
    const float* __restrict__ x, const float* __restrict__ g,
    const float* __restrict__ be,
    const float* __restrict__ mx0, const float* __restrict__ mx1,
    const float* __restrict__ mx2,
    ushort* __restrict__ o0, ushort* __restrict__ o1, ushort* __restrict__ o2,
    int T, int C) {
    const long row = blockIdx.x;
    const int t = (int)(row % T);
    const int tid = threadIdx.x;
    const int i0 = tid * 4;

    floatx4 xc = *(const floatx4*)&x[row * C + i0];
    floatx4 xp = (floatx4)0.f;
    if (t > 0) xp = *(const floatx4*)&x[(row - 1) * C + i0];

    float sc = xc.x + xc.y + xc.z + xc.w;
    float qc = xc.x * xc.x + xc.y * xc.y + xc.z * xc.z + xc.w * xc.w;
    float sp = xp.x + xp.y + xp.z + xp.w;
    float qp = xp.x * xp.x + xp.y * xp.y + xp.z * xp.z + xp.w * xp.w;

#pragma unroll
    for (int off = 32; off; off >>= 1) {
        sc += __shfl_xor(sc, off);
        qc += __shfl_xor(qc, off);
        sp += __shfl_xor(sp, off);
        qp += __shfl_xor(qp, off);
    }
    __shared__ float part[4][4];
    const int wv = tid >> 6;
    if ((tid & 63) == 0) {
        part[wv][0] = sc; part[wv][1] = qc; part[wv][2] = sp; part[wv][3] = qp;
    }
    __syncthreads();
    sc = part[0][0] + part[1][0] + part[2][0] + part[3][0];
    qc = part[0][1] + part[1][1] + part[2][1] + part[3][1];
    sp = part[0][2] + part[1][2] + part[2][2] + part[3][2];
    qp = part[0][3] + part[1][3] + part[2][3] + part[3][3];

    const float invC = 1.f / (float)C;
    float muc = sc * invC;
    float rsc = rsqrtf(qc * invC - muc * muc + LN_EPS);
    float mup = sp * invC;
    float rsp = rsqrtf(qp * invC - mup * mup + LN_EPS);

    floatx4 gv = *(const floatx4*)&g[i0];
    floatx4 bv = *(const floatx4*)&be[i0];
    floatx4 hc = (xc - muc) * rsc * gv + bv;
    floatx4 hp = (floatx4)0.f;
    if (t > 0) hp = (xp - mup) * rsp * gv + bv;

    {
        floatx4 mk = *(const floatx4*)&mx0[i0];
        floatx4 v = hc * mk + hp * (1.f - mk);
        ushort4 pk;
        pk.x = f2bf(v.x); pk.y = f2bf(v.y); pk.z = f2bf(v.z); pk.w = f2bf(v.w);
        *(ushort4*)&o0[row * C + i0] = pk;
    }
    {
        floatx4 mk = *(const floatx4*)&mx1[i0];
        floatx4 v = hc * mk + hp * (1.f - mk);
        ushort4 pk;
        pk.x = f2bf(v.x); pk.y = f2bf(v.y); pk.z = f2bf(v.z); pk.w = f2bf(v.w);
        *(ushort4*)&o1[row * C + i0] = pk;
    }
    {
        floatx4 mk = *(const floatx4*)&mx2[i0];
        floatx4 v = hc * mk + hp * (1.f - mk);
        ushort4 pk;
        pk.x = f2bf(v.x); pk.y = f2bf(v.y); pk.z = f2bf(v.z); pk.w = f2bf(v.w);
        *(ushort4*)&o2[row * C + i0] = pk;
    }
}

// ---------------------------------------------------------------------------
// Fused: out = x + ry (residual), then LayerNorm(out) + shift + 2 mixes.
// Recomputes row-1's x+ry locally (no cross-block dependency).
// ---------------------------------------------------------------------------
__global__ __launch_bounds__(256) void ln_mix_add(
    const float* __restrict__ x, const ushort* __restrict__ ry,
    const float* __restrict__ g, const float* __restrict__ be,
    const float* __restrict__ mx0, const float* __restrict__ mx1,
    float* __restrict__ outx,
    ushort* __restrict__ o0, ushort* __restrict__ o1, int T, int C) {
    const long row = blockIdx.x;
    const int t = (int)(row % T);
    const int tid = threadIdx.x;
    const int i0 = tid * 4;

    floatx4 xc = *(const floatx4*)&x[row * C + i0];
    ushort4 rc = *(const ushort4*)&ry[row * C + i0];
    xc.x += bf2f(rc.x); xc.y += bf2f(rc.y); xc.z += bf2f(rc.z); xc.w += bf2f(rc.w);
    *(floatx4*)&outx[row * C + i0] = xc;

    floatx4 xp = (floatx4)0.f;
    if (t > 0) {
        xp = *(const floatx4*)&x[(row - 1) * C + i0];
        ushort4 rp = *(const ushort4*)&ry[(row - 1) * C + i0];
        xp.x += bf2f(rp.x); xp.y += bf2f(rp.y); xp.z += bf2f(rp.z); xp.w += bf2f(rp.w);
    }

    float sc = xc.x + xc.y + xc.z + xc.w;
    float qc = xc.x * xc.x + xc.y * xc.y + xc.z * xc.z + xc.w * xc.w;
    float sp = xp.x + xp.y + xp.z + xp.w;
    float qp = xp.x * xp.x + xp.y * xp.y + xp.z * xp.z + xp.w * xp.w;

#pragma unroll
    for (int off = 32; off; off >>= 1) {
        sc += __shfl_xor(sc, off);
        qc += __shfl_xor(qc, off);
        sp += __shfl_xor(sp, off);
        qp += __shfl_xor(qp, off);
    }
    __shared__ float part[4][4];
    const int wv = tid >> 6;
    if ((tid & 63) == 0) {
        part[wv][0] = sc; part[wv][1] = qc; part[wv][2] = sp; part[wv][3] = qp;
    }
    __syncthreads();
    sc = part[0][0] + part[1][0] + part[2][0] + part[3][0];
    qc = part[0][1] + part[1][1] + part[2][1] + part[3][1];
    sp = part[0][2] + part[1][2] + part[2][2] + part[3][2];
    qp = part[0][3] + part[1][3] + part[2][3] + part[3][3];

    const float invC = 1.f / (float)C;
    float muc = sc * invC;
    float rsc = rsqrtf(qc * invC - muc * muc + LN_EPS);
    float mup = sp * invC;
    float rsp = rsqrtf(qp * invC - mup * mup + LN_EPS);

    floatx4 gv = *(const floatx4*)&g[i0];
    floatx4 bv = *(const floatx4*)&be[i0];
    floatx4 hc = (xc - muc) * rsc * gv + bv;
    floatx4 hp = (floatx4)0.f;
    if (t > 0) hp = (xp - mup) * rsp * gv + bv;

    {
        floatx4 mk = *(const floatx4*)&mx0[i0];
        floatx4 v = hc * mk + hp * (1.f - mk);
        ushort4 pk;
        pk.x = f2bf(v.x); pk.y = f2bf(v.y); pk.z = f2bf(v.z); pk.w = f2bf(v.w);
        *(ushort4*)&o0[row * C + i0] = pk;
    }
    {
        floatx4 mk = *(const floatx4*)&mx1[i0];
        floatx4 v = hc * mk + hp * (1.f - mk);
        ushort4 pk;
        pk.x = f2bf(v.x); pk.y = f2bf(v.y); pk.z = f2bf(v.z); pk.w = f2bf(v.w);
        *(ushort4*)&o1[row * C + i0] = pk;
    }
}

// ---------------------------------------------------------------------------
// WKV scan over transposed k/v/r ([C][Mtot], contiguous in t per lane).
// 32-step rounds (64 B/stream), one full round of register prefetch so the
// ~900-cy per-lane line-miss latency is covered by ~2900 cy of serial math.
// All log-space math in base 2 (raw v_exp_f32 / v_log_f32).
// ---------------------------------------------------------------------------
__global__ __launch_bounds__(64) void wkv_scan_t(
    const float* __restrict__ w, const float* __restrict__ u,
    const ushort* __restrict__ kT, const ushort* __restrict__ vT,
    const ushort* __restrict__ rT, ushort* __restrict__ ry,
    int T, int Mtot, int C) {
    const int gc = blockIdx.x * 64 + threadIdx.x;
    const int b = gc / C;
    const int c = gc - b * C;
    const long rowb = (long)c * Mtot + (long)b * T;
    const short8* kp = (const short8*)(kT + rowb);
    const short8* vp = (const short8*)(vT + rowb);
    const short8* rp = (const short8*)(rT + rowb);
    ushort* op = ry + (long)b * T * C + c;

    const float L2E = 1.4426950408889634f;
    const float w2 = w[c] * L2E, u2 = u[c] * L2E;

    float aa = 0.f, pp = -1e38f;  // pp in log2 domain
    short8 kc[4], vc[4], rc[4];
#pragma unroll
    for (int q = 0; q < 4; q++) { kc[q] = kp[q]; vc[q] = vp[q]; rc[q] = rp[q]; }

    for (int t0 = 0; t0 < T; t0 += 32) {
        const int nb = (t0 >> 3) + 4;  // next round base (in short8 units)
        short8 kn[4], vn[4], rn[4];
        if (t0 + 32 < T) {
#pragma unroll
            for (int q = 0; q < 4; q++) {
                kn[q] = kp[nb + q]; vn[q] = vp[nb + q]; rn[q] = rp[nb + q];
            }
        }
#pragma unroll
        for (int q = 0; q < 4; q++) {
#pragma unroll
            for (int j = 0; j < 8; ++j) {
                float kk = bf2f((ushort)kc[q][j]) * L2E;
                float vv = bf2f((ushort)vc[q][j]);
                float uk = u2 + kk;
                float p = fmaxf(pp, uk);
                float e1 = exp2f(pp - p);
                float e2 = exp2f(uk - p);
                float y = __fdividef(e1 * aa + e2 * vv, e1 + e2);
                op[(long)(t0 + q * 8 + j) * C] =
                    f2bf(bf2f((ushort)rc[q][j]) * y);
                float ppw = pp + w2;
                float wk = w2 + kk;
                float p2 = fmaxf(ppw, wk);
                float e1u = exp2f(ppw - p2);
                float e2u = exp2f(wk - p2);
                aa = e1u * aa + e2u * vv;
                pp = p2 + log2f(e1u + e2u);
            }
            kc[q] = kn[q]; vc[q] = vn[q]; rc[q] = rn[q];
        }
    }
}

// out[n][k] = bf16(in[k][n]); in is [K][N] fp32 row-major. block (32,8).
__global__ __launch_bounds__(256) void transpose_bf16(
    const float* __restrict__ in, ushort* __restrict__ out, int K, int N) {
    __shared__ float tile[32][33];
    const int tx = threadIdx.x, ty = threadIdx.y;
    const long k0 = (long)blockIdx.y * 32, n0 = (long)blockIdx.x * 32;
#pragma unroll
    for (int i = 0; i < 4; i++)
        tile[ty + i * 8][tx] = in[(k0 + ty + i * 8) * N + n0 + tx];
    __syncthreads();
#pragma unroll
    for (int i = 0; i < 4; i++)
        out[(n0 + ty + i * 8) * K + k0 + tx] = f2bf(tile[tx][ty + i * 8]);
}

extern "C" void kernel_launch(void* const* d_in, const int* in_sizes, int n_in,
                              void* d_out, int out_size, void* d_ws, size_t ws_size,
                              hipStream_t stream) {
    const float* x      = (const float*)d_in[0];
    const float* tdecay = (const float*)d_in[1];
    const float* tfirst = (const float*)d_in[2];
    const float* w_tk   = (const float*)d_in[3];
    const float* w_tv   = (const float*)d_in[4];
    const float* w_tr   = (const float*)d_in[5];
    const float* w_ck   = (const float*)d_in[6];
    const float* w_cv   = (const float*)d_in[7];
    const float* w_cr   = (const float*)d_in[8];
    const float* ln1g   = (const float*)d_in[9];
    const float* ln1b   = (const float*)d_in[10];
    const float* ln2g   = (const float*)d_in[11];
    const float* ln2b   = (const float*)d_in[12];
    const float* mixk   = (const float*)d_in[13];
    const float* mixv   = (const float*)d_in[14];
    const float* mixr   = (const float*)d_in[15];
    const float* cmixk  = (const float*)d_in[16];
    const float* cmixr  = (const float*)d_in[17];
    float* out = (float*)d_out;

    const int C  = in_sizes[1];              // 1024
    const long M = (long)in_sizes[0] / C;    // 16384
    const int T  = 2048;
    const int B  = (int)(M / T);
    const int H  = 2 * C;                    // 2048 = half of 4C

    // workspace layout (MB offsets), lifetime-reused, 184 MB total
    const size_t MBy = 1024ull * 1024ull;
    char* w8 = (char*)d_ws;
    ushort* wT_tk  = (ushort*)(w8 + 0 * MBy);
    ushort* wT_tv  = (ushort*)(w8 + 2 * MBy);
    ushort* wT_tr  = (ushort*)(w8 + 4 * MBy);
    ushort* wT_cr  = (ushort*)(w8 + 6 * MBy);
    ushort* wT_ck  = (ushort*)(w8 + 8 * MBy);    // [4096][1024]
    ushort* wT_cv0 = (ushort*)(w8 + 16 * MBy);   // [1024][2048]
    ushort* wT_cv1 = (ushort*)(w8 + 20 * MBy);   // [1024][2048]
    ushort* xk     = (ushort*)(w8 + 24 * MBy);
    ushort* xv     = (ushort*)(w8 + 56 * MBy);
    ushort* xr     = (ushort*)(w8 + 88 * MBy);
    ushort* kT     = (ushort*)(w8 + 120 * MBy);  // [C][M]
    ushort* vT     = (ushort*)(w8 + 152 * MBy);  // [C][M]
    ushort* rT     = (ushort*)(w8 + 24 * MBy);   // [C][M], xk dead
    ushort* ry     = (ushort*)(w8 + 56 * MBy);   // [M][C], xv dead
    ushort* ck     = (ushort*)(w8 + 88 * MBy);   // xr dead
    ushort* cr     = (ushort*)(w8 + 120 * MBy);  // kT dead
    ushort* scr    = (ushort*)(w8 + 152 * MBy);  // vT dead
    ushort* kkbuf  = (ushort*)(w8 + 24 * MBy);   // rT dead, 64MB [24,88)

    dim3 tb(32, 8);
    transpose_bf16<<<dim3(C / 32, C / 32), tb, 0, stream>>>(w_tk, wT_tk, C, C);
    transpose_bf16<<<dim3(C / 32, C / 32), tb, 0, stream>>>(w_tv, wT_tv, C, C);
    transpose_bf16<<<dim3(C / 32, C / 32), tb, 0, stream>>>(w_tr, wT_tr, C, C);
    transpose_bf16<<<dim3(C / 32, C / 32), tb, 0, stream>>>(w_cr, wT_cr, C, C);
    transpose_bf16<<<dim3(4 * C / 32, C / 32), tb, 0, stream>>>(w_ck, wT_ck, C, 4 * C);
    transpose_bf16<<<dim3(C / 32, H / 32), tb, 0, stream>>>(w_cv, wT_cv0, H, C);
    transpose_bf16<<<dim3(C / 32, H / 32), tb, 0, stream>>>(w_cv + (long)H * C, wT_cv1, H, C);

    ln_mix3<<<(int)M, 256, 0, stream>>>(x, ln1g, ln1b, mixk, mixv, mixr,
                                        xk, xv, xr, T, C);

    dim3 gsq(C / 128, (int)(M / 128));
    // k,v,r GEMMs write TRANSPOSED [C][M] for the scan (ldc = M)
    gemm_bt<4><<<gsq, 256, 0, stream>>>(xk, wT_tk, C, C, C, C, (int)M,
                                        nullptr, kT, nullptr, nullptr);
    gemm_bt<4><<<gsq, 256, 0, stream>>>(xv, wT_tv, C, C, C, C, (int)M,
                                        nullptr, vT, nullptr, nullptr);
    gemm_bt<5><<<gsq, 256, 0, stream>>>(xr, wT_tr, C, C, C, C, (int)M,
                                        nullptr, rT, nullptr, nullptr);

    wkv_scan_t<<<(B * C) / 64, 64, 0, stream>>>(tdecay, tfirst, kT, vT, rT,
                                                ry, T, (int)M, C);

    // fused: out = x + ry, then LN2 + shift + channel mixes
    ln_mix_add<<<(int)M, 256, 0, stream>>>(x, ry, ln2g, ln2b, cmixk, cmixr,
                                           out, ck, cr, T, C);

    gemm_bt<1><<<gsq, 256, 0, stream>>>(cr, wT_cr, C, C, C, C, C,
                                        nullptr, scr, nullptr, nullptr);

    // channel-mix hidden (4C) processed in two 2C halves through one 64MB buffer
    for (int h = 0; h < 2; ++h) {
        const ushort* wck_h = wT_ck + (long)h * H * C;   // rows [h*2C, h*2C+2C)
        const ushort* wcv_h = (h == 0) ? wT_cv0 : wT_cv1;
        gemm_bt<2><<<dim3(H / 128, (int)(M / 128)), 256, 0, stream>>>(
            ck, wck_h, H, C, C, C, H, nullptr, kkbuf, nullptr, nullptr);
        gemm_bt<3><<<gsq, 256, 0, stream>>>(
            kkbuf, wcv_h, C, H, H, H, C, out, nullptr, out, scr);
    }
}

// Round 5
// 977.709 us; speedup vs baseline: 1.1663x; 1.1663x over previous
//
#include <hip/hip_runtime.h>
#include <hip/hip_bf16.h>
#include <stdint.h>

#define LN_EPS 1e-5f

typedef __attribute__((ext_vector_type(8))) __bf16 bf16x8;
typedef __attribute__((ext_vector_type(8))) short short8;
typedef __attribute__((ext_vector_type(4))) float floatx4;

__device__ __forceinline__ ushort f2bf(float f) {
    __hip_bfloat16 h = __float2bfloat16(f);
    return *reinterpret_cast<ushort*>(&h);
}
__device__ __forceinline__ float bf2f(ushort u) {
    return __builtin_bit_cast(float, ((unsigned int)u) << 16);
}

// async global->LDS, 16B per lane; LDS dest = wave-uniform base + lane*16
__device__ __forceinline__ void gload16(const void* g, void* l) {
#if __has_builtin(__builtin_amdgcn_global_load_lds)
    __builtin_amdgcn_global_load_lds(
        (const __attribute__((address_space(1))) unsigned int*)g,
        (__attribute__((address_space(3))) unsigned int*)l, 16, 0, 0);
#else
    *(int4*)l = *(const int4*)g;
#endif
}

// ---------------------------------------------------------------------------
// GEMM: C[M,N] = A[M,K](bf16 rm, lda) x Bt[N,K](bf16 rm, ldb)  (Bt = B^T)
// 128x128 tile, BK=32, 256 thr (4 waves 2x2 of 64x64), mfma 16x16x32 bf16.
// EPI: 0 bf16 | 1 bf16 sigmoid | 2 bf16 relu^2 | 3 f32 out=add0+mul0*acc
// ---------------------------------------------------------------------------
template <int EPI>
__global__ __launch_bounds__(256, 2) void gemm_bt(
    const ushort* __restrict__ A, const ushort* __restrict__ Bt,
    int N, int K, int lda, int ldb, int ldc,
    float* __restrict__ outF, ushort* __restrict__ outB,
    const float* __restrict__ add0, const ushort* __restrict__ mul0) {
    __shared__ __align__(16) ushort As[128 * 32];
    __shared__ __align__(16) ushort Bs[128 * 32];

    const int tid  = threadIdx.x;
    const int lane = tid & 63;
    const int wv   = tid >> 6;
    const int quad = lane >> 4;
    const int l16  = lane & 15;
    const int wm   = (wv >> 1) * 64;
    const int wn   = (wv & 1) * 64;
    const long m0 = (long)blockIdx.y * 128;
    const long n0 = (long)blockIdx.x * 128;

    floatx4 acc[4][4];
#pragma unroll
    for (int i = 0; i < 4; i++)
#pragma unroll
        for (int j = 0; j < 4; j++) acc[i][j] = (floatx4)0.f;

    const int ci0 = tid, ci1 = tid + 256;
    const int r0 = ci0 >> 2, kc0 = (ci0 & 3) * 8;
    const int r1 = ci1 >> 2, kc1 = (ci1 & 3) * 8;
    const ushort* Ab0 = A + (m0 + r0) * (long)lda + kc0;
    const ushort* Ab1 = A + (m0 + r1) * (long)lda + kc1;
    const ushort* Bb0 = Bt + (n0 + r0) * (long)ldb + kc0;
    const ushort* Bb1 = Bt + (n0 + r1) * (long)ldb + kc1;

    for (int k0 = 0; k0 < K; k0 += 32) {
        gload16(Ab0 + k0, &As[ci0 * 8]);
        gload16(Ab1 + k0, &As[ci1 * 8]);
        gload16(Bb0 + k0, &Bs[ci0 * 8]);
        gload16(Bb1 + k0, &Bs[ci1 * 8]);
        __syncthreads();

        bf16x8 a[4], b[4];
#pragma unroll
        for (int mi = 0; mi < 4; mi++)
            a[mi] = __builtin_bit_cast(
                bf16x8, *(const short8*)&As[(wm + mi * 16 + l16) * 32 + quad * 8]);
#pragma unroll
        for (int ni = 0; ni < 4; ni++)
            b[ni] = __builtin_bit_cast(
                bf16x8, *(const short8*)&Bs[(wn + ni * 16 + l16) * 32 + quad * 8]);
#pragma unroll
        for (int mi = 0; mi < 4; mi++)
#pragma unroll
            for (int ni = 0; ni < 4; ni++)
                acc[mi][ni] = __builtin_amdgcn_mfma_f32_16x16x32_bf16(
                    a[mi], b[ni], acc[mi][ni], 0, 0, 0);
        __syncthreads();
    }

    // C/D layout: col = lane&15, row = quad*4 + reg (m89/m91-verified)
#pragma unroll
    for (int mi = 0; mi < 4; mi++) {
#pragma unroll
        for (int ni = 0; ni < 4; ni++) {
            long n = n0 + wn + ni * 16 + l16;
#pragma unroll
            for (int r = 0; r < 4; r++) {
                long m = m0 + wm + mi * 16 + quad * 4 + r;
                long idx = m * (long)ldc + n;
                float v = acc[mi][ni][r];
                if constexpr (EPI == 0) {
                    outB[idx] = f2bf(v);
                } else if constexpr (EPI == 1) {
                    outB[idx] = f2bf(1.f / (1.f + __expf(-v)));
                } else if constexpr (EPI == 2) {
                    float t = fmaxf(v, 0.f);
                    outB[idx] = f2bf(t * t);
                } else if constexpr (EPI == 3) {
                    outF[idx] = add0[idx] + bf2f(mul0[idx]) * v;
                }
            }
        }
    }
}

// ---------------------------------------------------------------------------
// Fused LayerNorm + time-shift + mix -> bf16 outputs (3 mixes), f32 input.
// ---------------------------------------------------------------------------
__global__ __launch_bounds__(256) void ln_mix3(
    const float* __restrict__ x, const float* __restrict__ g,
    const float* __restrict__ be,
    const float* __restrict__ mx0, const float* __restrict__ mx1,
    const float* __restrict__ mx2,
    ushort* __restrict__ o0, ushort* __restrict__ o1, ushort* __restrict__ o2,
    int T, int C) {
    const long row = blockIdx.x;
    const int t = (int)(row % T);
    const int tid = threadIdx.x;
    const int i0 = tid * 4;

    floatx4 xc = *(const floatx4*)&x[row * C + i0];
    floatx4 xp = (floatx4)0.f;
    if (t > 0) xp = *(const floatx4*)&x[(row - 1) * C + i0];

    float sc = xc.x + xc.y + xc.z + xc.w;
    float qc = xc.x * xc.x + xc.y * xc.y + xc.z * xc.z + xc.w * xc.w;
    float sp = xp.x + xp.y + xp.z + xp.w;
    float qp = xp.x * xp.x + xp.y * xp.y + xp.z * xp.z + xp.w * xp.w;

#pragma unroll
    for (int off = 32; off; off >>= 1) {
        sc += __shfl_xor(sc, off);
        qc += __shfl_xor(qc, off);
        sp += __shfl_xor(sp, off);
        qp += __shfl_xor(qp, off);
    }
    __shared__ float part[4][4];
    const int wv = tid >> 6;
    if ((tid & 63) == 0) {
        part[wv][0] = sc; part[wv][1] = qc; part[wv][2] = sp; part[wv][3] = qp;
    }
    __syncthreads();
    sc = part[0][0] + part[1][0] + part[2][0] + part[3][0];
    qc = part[0][1] + part[1][1] + part[2][1] + part[3][1];
    sp = part[0][2] + part[1][2] + part[2][2] + part[3][2];
    qp = part[0][3] + part[1][3] + part[2][3] + part[3][3];

    const float invC = 1.f / (float)C;
    float muc = sc * invC;
    float rsc = rsqrtf(qc * invC - muc * muc + LN_EPS);
    float mup = sp * invC;
    float rsp = rsqrtf(qp * invC - mup * mup + LN_EPS);

    floatx4 gv = *(const floatx4*)&g[i0];
    floatx4 bv = *(const floatx4*)&be[i0];
    floatx4 hc = (xc - muc) * rsc * gv + bv;
    floatx4 hp = (floatx4)0.f;
    if (t > 0) hp = (xp - mup) * rsp * gv + bv;

    {
        floatx4 mk = *(const floatx4*)&mx0[i0];
        floatx4 v = hc * mk + hp * (1.f - mk);
        ushort4 pk;
        pk.x = f2bf(v.x); pk.y = f2bf(v.y); pk.z = f2bf(v.z); pk.w = f2bf(v.w);
        *(ushort4*)&o0[row * C + i0] = pk;
    }
    {
        floatx4 mk = *(const floatx4*)&mx1[i0];
        floatx4 v = hc * mk + hp * (1.f - mk);
        ushort4 pk;
        pk.x = f2bf(v.x); pk.y = f2bf(v.y); pk.z = f2bf(v.z); pk.w = f2bf(v.w);
        *(ushort4*)&o1[row * C + i0] = pk;
    }
    {
        floatx4 mk = *(const floatx4*)&mx2[i0];
        floatx4 v = hc * mk + hp * (1.f - mk);
        ushort4 pk;
        pk.x = f2bf(v.x); pk.y = f2bf(v.y); pk.z = f2bf(v.z); pk.w = f2bf(v.w);
        *(ushort4*)&o2[row * C + i0] = pk;
    }
}

// ---------------------------------------------------------------------------
// Fused: out = x + ry (residual), then LayerNorm(out) + shift + 2 mixes.
// ---------------------------------------------------------------------------
__global__ __launch_bounds__(256) void ln_mix_add(
    const float* __restrict__ x, const ushort* __restrict__ ry,
    const float* __restrict__ g, const float* __restrict__ be,
    const float* __restrict__ mx0, const float* __restrict__ mx1,
    float* __restrict__ outx,
    ushort* __restrict__ o0, ushort* __restrict__ o1, int T, int C) {
    const long row = blockIdx.x;
    const int t = (int)(row % T);
    const int tid = threadIdx.x;
    const int i0 = tid * 4;

    floatx4 xc = *(const floatx4*)&x[row * C + i0];
    ushort4 rc = *(const ushort4*)&ry[row * C + i0];
    xc.x += bf2f(rc.x); xc.y += bf2f(rc.y); xc.z += bf2f(rc.z); xc.w += bf2f(rc.w);
    *(floatx4*)&outx[row * C + i0] = xc;

    floatx4 xp = (floatx4)0.f;
    if (t > 0) {
        xp = *(const floatx4*)&x[(row - 1) * C + i0];
        ushort4 rp = *(const ushort4*)&ry[(row - 1) * C + i0];
        xp.x += bf2f(rp.x); xp.y += bf2f(rp.y); xp.z += bf2f(rp.z); xp.w += bf2f(rp.w);
    }

    float sc = xc.x + xc.y + xc.z + xc.w;
    float qc = xc.x * xc.x + xc.y * xc.y + xc.z * xc.z + xc.w * xc.w;
    float sp = xp.x + xp.y + xp.z + xp.w;
    float qp = xp.x * xp.x + xp.y * xp.y + xp.z * xp.z + xp.w * xp.w;

#pragma unroll
    for (int off = 32; off; off >>= 1) {
        sc += __shfl_xor(sc, off);
        qc += __shfl_xor(qc, off);
        sp += __shfl_xor(sp, off);
        qp += __shfl_xor(qp, off);
    }
    __shared__ float part[4][4];
    const int wv = tid >> 6;
    if ((tid & 63) == 0) {
        part[wv][0] = sc; part[wv][1] = qc; part[wv][2] = sp; part[wv][3] = qp;
    }
    __syncthreads();
    sc = part[0][0] + part[1][0] + part[2][0] + part[3][0];
    qc = part[0][1] + part[1][1] + part[2][1] + part[3][1];
    sp = part[0][2] + part[1][2] + part[2][2] + part[3][2];
    qp = part[0][3] + part[1][3] + part[2][3] + part[3][3];

    const float invC = 1.f / (float)C;
    float muc = sc * invC;
    float rsc = rsqrtf(qc * invC - muc * muc + LN_EPS);
    float mup = sp * invC;
    float rsp = rsqrtf(qp * invC - mup * mup + LN_EPS);

    floatx4 gv = *(const floatx4*)&g[i0];
    floatx4 bv = *(const floatx4*)&be[i0];
    floatx4 hc = (xc - muc) * rsc * gv + bv;
    floatx4 hp = (floatx4)0.f;
    if (t > 0) hp = (xp - mup) * rsp * gv + bv;

    {
        floatx4 mk = *(const floatx4*)&mx0[i0];
        floatx4 v = hc * mk + hp * (1.f - mk);
        ushort4 pk;
        pk.x = f2bf(v.x); pk.y = f2bf(v.y); pk.z = f2bf(v.z); pk.w = f2bf(v.w);
        *(ushort4*)&o0[row * C + i0] = pk;
    }
    {
        floatx4 mk = *(const floatx4*)&mx1[i0];
        floatx4 v = hc * mk + hp * (1.f - mk);
        ushort4 pk;
        pk.x = f2bf(v.x); pk.y = f2bf(v.y); pk.z = f2bf(v.z); pk.w = f2bf(v.w);
        *(ushort4*)&o1[row * C + i0] = pk;
    }
}

// ===========================================================================
// Segmented exact WKV scan. T split into SEG segments of L steps.
// State (aa, pp): B=e^pp evolves linearly (composable); aa is affine in aa_in
// given the pp path (alpha = prod(e1u) in (0,1], beta bounded). base-2 domain.
// thread id g = ((b*SEG + s)*C + c); k/v/r in normal [M][C] layout.
// ===========================================================================

// K1: per-segment pp from zero state (reads k only)
__global__ __launch_bounds__(256) void wkv_pp_local(
    const float* __restrict__ w, const ushort* __restrict__ k,
    float* __restrict__ pp_loc, int C, int L) {
    const int g = blockIdx.x * 256 + threadIdx.x;
    const int c = g % C;
    const long seg = g / C;
    const float L2E = 1.4426950408889634f;
    const float w2 = w[c] * L2E;
    const ushort* kp = k + seg * L * C + c;
    float pp = -1e38f;
    for (int j = 0; j < L; ++j) {
        float kk = bf2f(kp[(long)j * C]) * L2E;
        float ppw = pp + w2;
        float wk = w2 + kk;
        float p2 = fmaxf(ppw, wk);
        pp = p2 + log2f(exp2f(ppw - p2) + exp2f(wk - p2));
    }
    pp_loc[g] = pp;
}

// K2: sequential pp composition per channel: B_out = 2^{w2*L} B_in + B_loc
__global__ __launch_bounds__(256) void wkv_pp_compose(
    const float* __restrict__ w, const float* __restrict__ pp_loc,
    float* __restrict__ pp_in, int C, int SEG, int L) {
    const int g = blockIdx.x * 256 + threadIdx.x;  // b*C + c
    const int c = g % C;
    const long b = g / C;
    const float wL = w[c] * 1.4426950408889634f * (float)L;
    float pp = -1e38f;
    for (int s = 0; s < SEG; ++s) {
        const long idx = (b * SEG + s) * C + c;
        pp_in[idx] = pp;
        float lhs = pp + wL;
        float rhs = pp_loc[idx];
        float m = fmaxf(lhs, rhs);
        pp = m + log2f(exp2f(lhs - m) + exp2f(rhs - m));
    }
}

// K3: per-segment (alpha,beta) on the TRUE pp path: aa_out = alpha*aa_in + beta
__global__ __launch_bounds__(256) void wkv_ab_local(
    const float* __restrict__ w, const ushort* __restrict__ k,
    const ushort* __restrict__ v, const float* __restrict__ pp_in,
    float* __restrict__ alpha, float* __restrict__ beta, int C, int L) {
    const int g = blockIdx.x * 256 + threadIdx.x;
    const int c = g % C;
    const long seg = g / C;
    const float L2E = 1.4426950408889634f;
    const float w2 = w[c] * L2E;
    const ushort* kp = k + seg * L * C + c;
    const ushort* vp = v + seg * L * C + c;
    float pp = pp_in[g];
    float al = 1.f, be = 0.f;
    for (int j = 0; j < L; ++j) {
        float kk = bf2f(kp[(long)j * C]) * L2E;
        float vv = bf2f(vp[(long)j * C]);
        float ppw = pp + w2;
        float wk = w2 + kk;
        float p2 = fmaxf(ppw, wk);
        float e1u = exp2f(ppw - p2);
        float e2u = exp2f(wk - p2);
        al *= e1u;
        be = e1u * be + e2u * vv;
        pp = p2 + log2f(e1u + e2u);
    }
    alpha[g] = al;
    beta[g] = be;
}

// K4: sequential aa composition per channel
__global__ __launch_bounds__(256) void wkv_aa_compose(
    const float* __restrict__ alpha, const float* __restrict__ beta,
    float* __restrict__ aa_in, int C, int SEG) {
    const int g = blockIdx.x * 256 + threadIdx.x;  // b*C + c
    const int c = g % C;
    const long b = g / C;
    float aa = 0.f;
    for (int s = 0; s < SEG; ++s) {
        const long idx = (b * SEG + s) * C + c;
        aa_in[idx] = aa;
        aa = alpha[idx] * aa + beta[idx];
    }
    (void)c;
}

// K5: per-segment emit with true incoming state: ry = r * y, [M][C] layout
__global__ __launch_bounds__(256) void wkv_emit(
    const float* __restrict__ w, const float* __restrict__ u,
    const ushort* __restrict__ k, const ushort* __restrict__ v,
    const ushort* __restrict__ r, const float* __restrict__ aa_in,
    const float* __restrict__ pp_in, ushort* __restrict__ ry, int C, int L) {
    const int g = blockIdx.x * 256 + threadIdx.x;
    const int c = g % C;
    const long seg = g / C;
    const float L2E = 1.4426950408889634f;
    const float w2 = w[c] * L2E;
    const float u2 = u[c] * L2E;
    const long base = seg * L * C + c;
    const ushort* kp = k + base;
    const ushort* vp = v + base;
    const ushort* rp = r + base;
    ushort* op = ry + base;
    float aa = aa_in[g];
    float pp = pp_in[g];
    for (int j = 0; j < L; ++j) {
        const long o = (long)j * C;
        float kk = bf2f(kp[o]) * L2E;
        float vv = bf2f(vp[o]);
        float uk = u2 + kk;
        float p = fmaxf(pp, uk);
        float e1 = exp2f(pp - p);
        float e2 = exp2f(uk - p);
        float y = __fdividef(e1 * aa + e2 * vv, e1 + e2);
        op[o] = f2bf(bf2f(rp[o]) * y);
        float ppw = pp + w2;
        float wk = w2 + kk;
        float p2 = fmaxf(ppw, wk);
        float e1u = exp2f(ppw - p2);
        float e2u = exp2f(wk - p2);
        aa = e1u * aa + e2u * vv;
        pp = p2 + log2f(e1u + e2u);
    }
}

// out[n][k] = bf16(in[k][n]); in is [K][N] fp32 row-major. block (32,8).
__global__ __launch_bounds__(256) void transpose_bf16(
    const float* __restrict__ in, ushort* __restrict__ out, int K, int N) {
    __shared__ float tile[32][33];
    const int tx = threadIdx.x, ty = threadIdx.y;
    const long k0 = (long)blockIdx.y * 32, n0 = (long)blockIdx.x * 32;
#pragma unroll
    for (int i = 0; i < 4; i++)
        tile[ty + i * 8][tx] = in[(k0 + ty + i * 8) * N + n0 + tx];
    __syncthreads();
#pragma unroll
    for (int i = 0; i < 4; i++)
        out[(n0 + ty + i * 8) * K + k0 + tx] = f2bf(tile[tx][ty + i * 8]);
}

extern "C" void kernel_launch(void* const* d_in, const int* in_sizes, int n_in,
                              void* d_out, int out_size, void* d_ws, size_t ws_size,
                              hipStream_t stream) {
    const float* x      = (const float*)d_in[0];
    const float* tdecay = (const float*)d_in[1];
    const float* tfirst = (const float*)d_in[2];
    const float* w_tk   = (const float*)d_in[3];
    const float* w_tv   = (const float*)d_in[4];
    const float* w_tr   = (const float*)d_in[5];
    const float* w_ck   = (const float*)d_in[6];
    const float* w_cv   = (const float*)d_in[7];
    const float* w_cr   = (const float*)d_in[8];
    const float* ln1g   = (const float*)d_in[9];
    const float* ln1b   = (const float*)d_in[10];
    const float* ln2g   = (const float*)d_in[11];
    const float* ln2b   = (const float*)d_in[12];
    const float* mixk   = (const float*)d_in[13];
    const float* mixv   = (const float*)d_in[14];
    const float* mixr   = (const float*)d_in[15];
    const float* cmixk  = (const float*)d_in[16];
    const float* cmixr  = (const float*)d_in[17];
    float* out = (float*)d_out;

    const int C  = in_sizes[1];              // 1024
    const long M = (long)in_sizes[0] / C;    // 16384
    const int T  = 2048;
    const int B  = (int)(M / T);
    const int H  = 2 * C;                    // 2048 = half of 4C
    const int SEG = 64;                      // segments per sequence
    const int L  = T / SEG;                  // 32 steps per segment
    const int NSEG = B * SEG;                // 512 total segments

    // workspace (MB offsets), lifetime-reused, max 184 MB:
    //  0..24  weights
    // 24: xk -> rbuf -> scr
    // 56: xv -> states(10MB: pp_loc 56, pp_in 58, alpha 60, beta 62, aa_in 64)
    //         -> kkbuf[56..120)
    // 88: xr -> ry
    // 120: kbuf -> ck
    // 152: vbuf -> cr
    const size_t MBy = 1024ull * 1024ull;
    char* w8 = (char*)d_ws;
    ushort* wT_tk  = (ushort*)(w8 + 0 * MBy);
    ushort* wT_tv  = (ushort*)(w8 + 2 * MBy);
    ushort* wT_tr  = (ushort*)(w8 + 4 * MBy);
    ushort* wT_cr  = (ushort*)(w8 + 6 * MBy);
    ushort* wT_ck  = (ushort*)(w8 + 8 * MBy);
    ushort* wT_cv0 = (ushort*)(w8 + 16 * MBy);
    ushort* wT_cv1 = (ushort*)(w8 + 20 * MBy);
    ushort* xk     = (ushort*)(w8 + 24 * MBy);
    ushort* xv     = (ushort*)(w8 + 56 * MBy);
    ushort* xr     = (ushort*)(w8 + 88 * MBy);
    ushort* kbuf   = (ushort*)(w8 + 120 * MBy);
    ushort* vbuf   = (ushort*)(w8 + 152 * MBy);
    ushort* rbuf   = (ushort*)(w8 + 24 * MBy);   // xk dead
    float*  pp_loc = (float*)(w8 + 56 * MBy);    // xv dead (2MB each)
    float*  pp_in  = (float*)(w8 + 58 * MBy);
    float*  alpha  = (float*)(w8 + 60 * MBy);
    float*  beta   = (float*)(w8 + 62 * MBy);
    float*  aa_in  = (float*)(w8 + 64 * MBy);
    ushort* ry     = (ushort*)(w8 + 88 * MBy);   // xr dead
    ushort* ck     = (ushort*)(w8 + 120 * MBy);  // kbuf dead
    ushort* cr     = (ushort*)(w8 + 152 * MBy);  // vbuf dead
    ushort* scr    = (ushort*)(w8 + 24 * MBy);   // rbuf dead
    ushort* kkbuf  = (ushort*)(w8 + 56 * MBy);   // states/ry dead, 64MB

    dim3 tb(32, 8);
    transpose_bf16<<<dim3(C / 32, C / 32), tb, 0, stream>>>(w_tk, wT_tk, C, C);
    transpose_bf16<<<dim3(C / 32, C / 32), tb, 0, stream>>>(w_tv, wT_tv, C, C);
    transpose_bf16<<<dim3(C / 32, C / 32), tb, 0, stream>>>(w_tr, wT_tr, C, C);
    transpose_bf16<<<dim3(C / 32, C / 32), tb, 0, stream>>>(w_cr, wT_cr, C, C);
    transpose_bf16<<<dim3(4 * C / 32, C / 32), tb, 0, stream>>>(w_ck, wT_ck, C, 4 * C);
    transpose_bf16<<<dim3(C / 32, H / 32), tb, 0, stream>>>(w_cv, wT_cv0, H, C);
    transpose_bf16<<<dim3(C / 32, H / 32), tb, 0, stream>>>(w_cv + (long)H * C, wT_cv1, H, C);

    ln_mix3<<<(int)M, 256, 0, stream>>>(x, ln1g, ln1b, mixk, mixv, mixr,
                                        xk, xv, xr, T, C);

    dim3 gsq(C / 128, (int)(M / 128));
    gemm_bt<0><<<gsq, 256, 0, stream>>>(xk, wT_tk, C, C, C, C, C,
                                        nullptr, kbuf, nullptr, nullptr);
    gemm_bt<0><<<gsq, 256, 0, stream>>>(xv, wT_tv, C, C, C, C, C,
                                        nullptr, vbuf, nullptr, nullptr);
    gemm_bt<1><<<gsq, 256, 0, stream>>>(xr, wT_tr, C, C, C, C, C,
                                        nullptr, rbuf, nullptr, nullptr);

    // segmented exact WKV scan
    const int segthreads = NSEG * C;                     // 524288
    wkv_pp_local<<<segthreads / 256, 256, 0, stream>>>(tdecay, kbuf, pp_loc, C, L);
    wkv_pp_compose<<<(B * C) / 256, 256, 0, stream>>>(tdecay, pp_loc, pp_in, C, SEG, L);
    wkv_ab_local<<<segthreads / 256, 256, 0, stream>>>(tdecay, kbuf, vbuf, pp_in,
                                                       alpha, beta, C, L);
    wkv_aa_compose<<<(B * C) / 256, 256, 0, stream>>>(alpha, beta, aa_in, C, SEG);
    wkv_emit<<<segthreads / 256, 256, 0, stream>>>(tdecay, tfirst, kbuf, vbuf, rbuf,
                                                   aa_in, pp_in, ry, C, L);

    // fused: out = x + ry, then LN2 + shift + channel mixes
    ln_mix_add<<<(int)M, 256, 0, stream>>>(x, ry, ln2g, ln2b, cmixk, cmixr,
                                           out, ck, cr, T, C);

    gemm_bt<1><<<gsq, 256, 0, stream>>>(cr, wT_cr, C, C, C, C, C,
                                        nullptr, scr, nullptr, nullptr);

    // channel-mix hidden (4C) processed in two 2C halves through one 64MB buffer
    for (int h = 0; h < 2; ++h) {
        const ushort* wck_h = wT_ck + (long)h * H * C;
        const ushort* wcv_h = (h == 0) ? wT_cv0 : wT_cv1;
        gemm_bt<2><<<dim3(H / 128, (int)(M / 128)), 256, 0, stream>>>(
            ck, wck_h, H, C, C, C, H, nullptr, kkbuf, nullptr, nullptr);
        gemm_bt<3><<<gsq, 256, 0, stream>>>(
            kkbuf, wcv_h, C, H, H, H, C, out, nullptr, out, scr);
    }
}